// Round 1
// baseline (1726.987 us; speedup 1.0000x reference)
//
#include <hip/hip_runtime.h>

typedef unsigned short u16;
typedef unsigned int u32;
typedef u16 u16x8 __attribute__((ext_vector_type(8)));
typedef __bf16 bf16x8 __attribute__((ext_vector_type(8)));
typedef float f32x4 __attribute__((ext_vector_type(4)));

#define DEV __device__ __forceinline__

DEV u16 f2bf(float f) {
  u32 u = __builtin_bit_cast(u32, f);
  u32 r = u + 0x7fffu + ((u >> 16) & 1u);
  return (u16)(r >> 16);
}

DEV void gload_lds16(const void* g, void* l) {
  __builtin_amdgcn_global_load_lds(
      (const __attribute__((address_space(1))) void*)g,
      (__attribute__((address_space(3))) void*)l, 16, 0, 0);
}

// ---------------- GEMM: C[M,N] = A[M,K](bf16) @ Bt[N,K]^T(bf16) + bias ----------------
template <int RELU, int OUT_BF16>
__global__ __launch_bounds__(256, 2) void gemm_bf16_kernel(
    const u16* __restrict__ A, const u16* __restrict__ Bt,
    const float* __restrict__ bias, u16* __restrict__ Cb, float* __restrict__ Cf,
    int M, int N, int K) {
  __shared__ __align__(16) u16 As[128 * 64];
  __shared__ __align__(16) u16 Bs[128 * 64];
  const int t = threadIdx.x, wave = t >> 6, lane = t & 63;
  const int fr = lane & 15, fq = lane >> 4;
  const int nbx = N >> 7;
  const int bx = blockIdx.x % nbx, by = blockIdx.x / nbx;
  const int m0 = by << 7, n0 = bx << 7;

  const int srow = t >> 3, scol = (t & 7) * 8;
  const u16* ag = A + (size_t)(m0 + srow) * K + scol;
  const u16* bg = Bt + (size_t)(n0 + srow) * K + scol;
  char* asb = (char*)As + wave * 1024;
  char* bsb = (char*)Bs + wave * 1024;

  f32x4 acc[4][4] = {};
  const int wr = (wave >> 1) * 64, wc = (wave & 1) * 64;

  for (int k0 = 0; k0 < K; k0 += 64) {
#pragma unroll
    for (int i = 0; i < 4; ++i) {
      gload_lds16(ag + (size_t)i * 32 * K, asb + i * 4096);
      gload_lds16(bg + (size_t)i * 32 * K, bsb + i * 4096);
    }
    ag += 64;
    bg += 64;
    asm volatile("s_waitcnt vmcnt(0)" ::: "memory");
    __syncthreads();
#pragma unroll
    for (int ks = 0; ks < 2; ++ks) {
      bf16x8 af[4], bv[4];
#pragma unroll
      for (int m = 0; m < 4; ++m)
        af[m] = *(const bf16x8*)(As + (wr + m * 16 + fr) * 64 + ks * 32 + fq * 8);
#pragma unroll
      for (int n = 0; n < 4; ++n)
        bv[n] = *(const bf16x8*)(Bs + (wc + n * 16 + fr) * 64 + ks * 32 + fq * 8);
#pragma unroll
      for (int m = 0; m < 4; ++m)
#pragma unroll
        for (int n = 0; n < 4; ++n)
          acc[m][n] = __builtin_amdgcn_mfma_f32_16x16x32_bf16(af[m], bv[n], acc[m][n], 0, 0, 0);
    }
    __syncthreads();
  }

#pragma unroll
  for (int n = 0; n < 4; ++n) {
    const int col = n0 + wc + n * 16 + fr;
    const float bvv = bias[col];
#pragma unroll
    for (int m = 0; m < 4; ++m) {
#pragma unroll
      for (int r = 0; r < 4; ++r) {
        const int row = m0 + wr + m * 16 + fq * 4 + r;
        float v = acc[m][n][r] + bvv;
        if (RELU) v = fmaxf(v, 0.f);
        if (OUT_BF16)
          Cb[(size_t)row * N + col] = f2bf(v);
        else
          Cf[(size_t)row * N + col] = v;
      }
    }
  }
}

// ---------------- attention: qkv [B,S,2304] bf16 -> o [B,S,768] f32 ----------------
__global__ __launch_bounds__(256, 2) void attn_kernel(const u16* __restrict__ qkv,
                                                      const int* __restrict__ lens,
                                                      float* __restrict__ o) {
  __shared__ __align__(16) u16 Kl[128 * 64];
  __shared__ __align__(16) u16 Vt[64 * 128];
  __shared__ __align__(16) u16 Pl[4][16 * 128];

  const int bid = blockIdx.x;
  const int qt = bid & 7;
  const int h = (bid >> 3) % 12;
  const int b = bid / 96;
  const int len = lens[b];
  const int t = threadIdx.x, wave = t >> 6, lane = t & 63;
  const int fr = lane & 15, fq = lane >> 4;

  const size_t base = (size_t)b * 512 * 2304;
  const int q0 = qt * 64 + wave * 16;

  bf16x8 qf[2];
#pragma unroll
  for (int ks = 0; ks < 2; ++ks)
    qf[ks] = *(const bf16x8*)(qkv + base + (size_t)(q0 + fr) * 2304 + h * 64 + ks * 32 + fq * 8);

  f32x4 oacc[4] = {};
  float mrow[4], lrow[4];
#pragma unroll
  for (int r = 0; r < 4; ++r) {
    mrow[r] = -1e30f;
    lrow[r] = 0.f;
  }

  for (int kv0 = 0; kv0 < 512; kv0 += 128) {
    if (kv0 >= len) break;
    // stage K [128][64] and V^T [64][128], both chunk-XOR-swizzled
#pragma unroll
    for (int i = 0; i < 4; ++i) {
      const int c = i * 256 + t;
      const int row = c >> 3, ch = c & 7;
      u16x8 kvl = *(const u16x8*)(qkv + base + (size_t)(kv0 + row) * 2304 + 768 + h * 64 + ch * 8);
      *(u16x8*)(Kl + row * 64 + ((ch ^ (row & 7)) * 8)) = kvl;
      u16x8 vvl = *(const u16x8*)(qkv + base + (size_t)(kv0 + row) * 2304 + 1536 + h * 64 + ch * 8);
#pragma unroll
      for (int u = 0; u < 8; ++u) {
        const int d = ch * 8 + u;
        Vt[d * 128 + (((row >> 3) ^ (d & 7)) * 8) + (row & 7)] = vvl[u];
      }
    }
    __syncthreads();

    f32x4 sa[8] = {};
#pragma unroll
    for (int ks = 0; ks < 2; ++ks) {
#pragma unroll
      for (int n = 0; n < 8; ++n) {
        const int colr = n * 16 + fr;
        bf16x8 kf = *(const bf16x8*)(Kl + colr * 64 + (((ks * 4 + fq) ^ (colr & 7)) * 8));
        sa[n] = __builtin_amdgcn_mfma_f32_16x16x32_bf16(qf[ks], kf, sa[n], 0, 0, 0);
      }
    }

    float tm[4] = {-1e30f, -1e30f, -1e30f, -1e30f};
#pragma unroll
    for (int n = 0; n < 8; ++n) {
      const int col = kv0 + n * 16 + fr;
      const bool ok = col < len;
#pragma unroll
      for (int r = 0; r < 4; ++r) {
        const float s = ok ? sa[n][r] * 0.125f : -1e30f;
        sa[n][r] = s;
        tm[r] = fmaxf(tm[r], s);
      }
    }
#pragma unroll
    for (int d = 1; d < 16; d <<= 1)
#pragma unroll
      for (int r = 0; r < 4; ++r) tm[r] = fmaxf(tm[r], __shfl_xor(tm[r], d));

    float al[4], rs[4];
#pragma unroll
    for (int r = 0; r < 4; ++r) {
      const float mn = fmaxf(mrow[r], tm[r]);
      al[r] = __expf(mrow[r] - mn);
      mrow[r] = mn;
      rs[r] = 0.f;
    }
#pragma unroll
    for (int n = 0; n < 8; ++n)
#pragma unroll
      for (int r = 0; r < 4; ++r) {
        const float p = __expf(sa[n][r] - mrow[r]);
        sa[n][r] = p;
        rs[r] += p;
      }
#pragma unroll
    for (int d = 1; d < 16; d <<= 1)
#pragma unroll
      for (int r = 0; r < 4; ++r) rs[r] += __shfl_xor(rs[r], d);
#pragma unroll
    for (int r = 0; r < 4; ++r) lrow[r] = lrow[r] * al[r] + rs[r];
#pragma unroll
    for (int n = 0; n < 4; ++n)
#pragma unroll
      for (int r = 0; r < 4; ++r) oacc[n][r] *= al[r];

    u16* P = &Pl[wave][0];
#pragma unroll
    for (int n = 0; n < 8; ++n) {
      const int col = n * 16 + fr;
#pragma unroll
      for (int r = 0; r < 4; ++r) {
        const int row = fq * 4 + r;
        P[row * 128 + (((col >> 3) ^ (row & 7)) * 8) + (col & 7)] = f2bf(sa[n][r]);
      }
    }
    // PV (each wave reads only its own P region; in-wave lgkmcnt ordering suffices)
#pragma unroll
    for (int kslot = 0; kslot < 4; ++kslot) {
      const int ch = kslot * 4 + fq;
      bf16x8 pa = *(const bf16x8*)(P + fr * 128 + ((ch ^ (fr & 7)) * 8));
#pragma unroll
      for (int n = 0; n < 4; ++n) {
        const int colv = n * 16 + fr;
        bf16x8 vf = *(const bf16x8*)(Vt + colv * 128 + ((ch ^ (colv & 7)) * 8));
        oacc[n] = __builtin_amdgcn_mfma_f32_16x16x32_bf16(pa, vf, oacc[n], 0, 0, 0);
      }
    }
    __syncthreads();
  }

  const size_t obase = (size_t)b * 512 * 768 + (size_t)q0 * 768 + h * 64;
#pragma unroll
  for (int n = 0; n < 4; ++n)
#pragma unroll
    for (int r = 0; r < 4; ++r)
      o[obase + (size_t)(fq * 4 + r) * 768 + n * 16 + fr] = oacc[n][r] / lrow[r];
}

// ---------------- f32 -> bf16 transpose (out[n][k] = in[k][n]) ----------------
__global__ __launch_bounds__(256) void transpose_one_kernel(const float* __restrict__ in,
                                                            u16* __restrict__ outp, int K,
                                                            int N) {
  __shared__ float tile[64][65];
  const int tx = threadIdx.x & 63, ty = threadIdx.x >> 6;
  const int n0 = blockIdx.x * 64, k0 = blockIdx.y * 64;
#pragma unroll
  for (int i = 0; i < 16; ++i)
    tile[ty + i * 4][tx] = in[(size_t)(k0 + ty + i * 4) * N + n0 + tx];
  __syncthreads();
#pragma unroll
  for (int i = 0; i < 16; ++i)
    outp[(size_t)(n0 + ty + i * 4) * K + k0 + tx] = f2bf(tile[tx][ty + i * 4]);
}

__global__ __launch_bounds__(256) void transpose_qkv_kernel(const float* __restrict__ qw,
                                                            const float* __restrict__ kw,
                                                            const float* __restrict__ vw, int l,
                                                            u16* __restrict__ outp) {
  __shared__ float tile[64][65];
  const int which = blockIdx.z;
  const float* in = (which == 0 ? qw : which == 1 ? kw : vw) + (size_t)l * 768 * 768;
  u16* op = outp + (size_t)which * 768 * 768;
  const int tx = threadIdx.x & 63, ty = threadIdx.x >> 6;
  const int n0 = blockIdx.x * 64, k0 = blockIdx.y * 64;
#pragma unroll
  for (int i = 0; i < 16; ++i)
    tile[ty + i * 4][tx] = in[(size_t)(k0 + ty + i * 4) * 768 + n0 + tx];
  __syncthreads();
#pragma unroll
  for (int i = 0; i < 16; ++i)
    op[(size_t)(n0 + ty + i * 4) * 768 + k0 + tx] = f2bf(tile[tx][ty + i * 4]);
}

// ---------------- input projection: h = x@in_w + in_b + pos ----------------
__global__ __launch_bounds__(256) void inproj_kernel(const float* __restrict__ x,
                                                     const float* __restrict__ in_w,
                                                     const float* __restrict__ in_b,
                                                     const float* __restrict__ pos,
                                                     float* __restrict__ h,
                                                     u16* __restrict__ hbf) {
  __shared__ float xs[8][32];
  const int t = threadIdx.x;
  const int row0 = blockIdx.x * 8;
  xs[t >> 5][t & 31] = x[(size_t)row0 * 32 + t];
  __syncthreads();
#pragma unroll
  for (int j = 0; j < 3; ++j) {
    const int d = t + j * 256;
    float acc[8] = {};
#pragma unroll
    for (int i = 0; i < 32; ++i) {
      const float wv = in_w[i * 768 + d];
#pragma unroll
      for (int r = 0; r < 8; ++r) acc[r] += xs[r][i] * wv;
    }
    const float bb = in_b[d];
#pragma unroll
    for (int r = 0; r < 8; ++r) {
      const int row = row0 + r;
      const int s = row & 511;
      const float v = acc[r] + bb + pos[(size_t)s * 768 + d];
      h[(size_t)row * 768 + d] = v;
      hbf[(size_t)row * 768 + d] = f2bf(v);
    }
  }
}

// ---------------- LayerNorm(hin + delta) -> hout f32 + hbf bf16 ----------------
__global__ __launch_bounds__(256) void ln_kernel(const float* __restrict__ hin,
                                                 const float* __restrict__ delta,
                                                 const float* __restrict__ g,
                                                 const float* __restrict__ bb,
                                                 float* __restrict__ hout,
                                                 u16* __restrict__ hbf) {
  const int row = blockIdx.x, t = threadIdx.x;
  const size_t rb = (size_t)row * 768;
  float xv[3], s = 0.f, s2 = 0.f;
#pragma unroll
  for (int j = 0; j < 3; ++j) {
    const float v = hin[rb + t + j * 256] + delta[rb + t + j * 256];
    xv[j] = v;
    s += v;
    s2 += v * v;
  }
#pragma unroll
  for (int d = 1; d < 64; d <<= 1) {
    s += __shfl_xor(s, d);
    s2 += __shfl_xor(s2, d);
  }
  __shared__ float ws[8];
  if ((t & 63) == 0) {
    ws[t >> 6] = s;
    ws[4 + (t >> 6)] = s2;
  }
  __syncthreads();
  s = ws[0] + ws[1] + ws[2] + ws[3];
  s2 = ws[4] + ws[5] + ws[6] + ws[7];
  const float mean = s * (1.f / 768.f);
  const float var = fmaxf(s2 * (1.f / 768.f) - mean * mean, 0.f);
  const float rstd = rsqrtf(var + 1e-5f);
#pragma unroll
  for (int j = 0; j < 3; ++j) {
    const int d = t + j * 256;
    const float y = (xv[j] - mean) * rstd * g[d] + bb[d];
    hout[rb + d] = y;
    hbf[rb + d] = f2bf(y);
  }
}

// ---------------- masked mean pool + out projection ----------------
__global__ __launch_bounds__(256) void pool_kernel(const float* __restrict__ h,
                                                   const int* __restrict__ lens,
                                                   const float* __restrict__ ow,
                                                   const float* __restrict__ ob,
                                                   float* __restrict__ out) {
  const int b = blockIdx.x, t = threadIdx.x;
  const int len = lens[b];
  float acc0 = 0.f, acc1 = 0.f, acc2 = 0.f;
  const float* hp = h + (size_t)b * 512 * 768;
  for (int s = 0; s < len; ++s) {
    acc0 += hp[(size_t)s * 768 + t];
    acc1 += hp[(size_t)s * 768 + t + 256];
    acc2 += hp[(size_t)s * 768 + t + 512];
  }
  const float inv = 1.f / (float)len;
  float part = (acc0 * ow[t] + acc1 * ow[t + 256] + acc2 * ow[t + 512]) * inv;
#pragma unroll
  for (int d = 1; d < 64; d <<= 1) part += __shfl_xor(part, d);
  __shared__ float ps[4];
  if ((t & 63) == 0) ps[t >> 6] = part;
  __syncthreads();
  if (t == 0) out[b] = ps[0] + ps[1] + ps[2] + ps[3] + ob[0];
}

__global__ void biaspack_kernel(const float* __restrict__ qb, const float* __restrict__ kb,
                                const float* __restrict__ vb, float* __restrict__ qkvb) {
  const int i = blockIdx.x * 256 + threadIdx.x;
  if (i >= 6 * 2304) return;
  const int l = i / 2304, j = i % 2304;
  float v;
  if (j < 768)
    v = qb[l * 768 + j];
  else if (j < 1536)
    v = kb[l * 768 + j - 768];
  else
    v = vb[l * 768 + j - 1536];
  qkvb[i] = v;
}

extern "C" void kernel_launch(void* const* d_in, const int* in_sizes, int n_in, void* d_out,
                              int out_size, void* d_ws, size_t ws_size, hipStream_t stream) {
  const float* x = (const float*)d_in[0];
  const int* lens = (const int*)d_in[1];
  const float* in_w = (const float*)d_in[2];
  const float* in_b = (const float*)d_in[3];
  const float* pos = (const float*)d_in[4];
  const float* qw = (const float*)d_in[5];
  const float* qb = (const float*)d_in[6];
  const float* kw = (const float*)d_in[7];
  const float* kb = (const float*)d_in[8];
  const float* vw = (const float*)d_in[9];
  const float* vb = (const float*)d_in[10];
  const float* w1 = (const float*)d_in[11];
  const float* b1 = (const float*)d_in[12];
  const float* w2 = (const float*)d_in[13];
  const float* b2 = (const float*)d_in[14];
  const float* ln1g = (const float*)d_in[15];
  const float* ln1b = (const float*)d_in[16];
  const float* ln2g = (const float*)d_in[17];
  const float* ln2b = (const float*)d_in[18];
  const float* ow = (const float*)d_in[19];
  const float* ob = (const float*)d_in[20];
  float* out = (float*)d_out;

  char* w = (char*)d_ws;
  size_t off = 0;
  auto alloc = [&](size_t bytes) -> void* {
    void* p = w + off;
    off += (bytes + 255) & ~(size_t)255;
    return p;
  };
  u16* qkvt = (u16*)alloc((size_t)2304 * 768 * 2);
  u16* w1t = (u16*)alloc((size_t)3072 * 768 * 2);
  u16* w2t = (u16*)alloc((size_t)768 * 3072 * 2);
  float* qkvb = (float*)alloc((size_t)6 * 2304 * 4);
  float* h = (float*)alloc((size_t)8192 * 768 * 4);
  u16* hbf = (u16*)alloc((size_t)8192 * 768 * 2);
  float* obuf = (float*)alloc((size_t)8192 * 768 * 4);
  u16* ubuf = (u16*)alloc((size_t)8192 * 3072 * 2);  // union: qkv (8192x2304) / ff (8192x3072)
  u16* qkvbuf = ubuf;
  u16* ffbuf = ubuf;

  biaspack_kernel<<<(6 * 2304 + 255) / 256, 256, 0, stream>>>(qb, kb, vb, qkvb);
  inproj_kernel<<<1024, 256, 0, stream>>>(x, in_w, in_b, pos, h, hbf);

  for (int l = 0; l < 6; ++l) {
    transpose_qkv_kernel<<<dim3(12, 12, 3), 256, 0, stream>>>(qw, kw, vw, l, qkvt);
    gemm_bf16_kernel<0, 1><<<64 * 18, 256, 0, stream>>>(hbf, qkvt, qkvb + l * 2304, qkvbuf,
                                                        nullptr, 8192, 2304, 768);
    attn_kernel<<<1536, 256, 0, stream>>>(qkvbuf, lens, obuf);
    ln_kernel<<<8192, 256, 0, stream>>>(h, obuf, ln1g + l * 768, ln1b + l * 768, h, hbf);
    transpose_one_kernel<<<dim3(48, 12), 256, 0, stream>>>(w1 + (size_t)l * 768 * 3072, w1t, 768,
                                                           3072);
    gemm_bf16_kernel<1, 1><<<64 * 24, 256, 0, stream>>>(hbf, w1t, b1 + l * 3072, ffbuf, nullptr,
                                                        8192, 3072, 768);
    transpose_one_kernel<<<dim3(12, 48), 256, 0, stream>>>(w2 + (size_t)l * 3072 * 768, w2t, 3072,
                                                           768);
    gemm_bf16_kernel<0, 0><<<64 * 6, 256, 0, stream>>>(ffbuf, w2t, b2 + l * 768, nullptr, obuf,
                                                       8192, 768, 3072);
    ln_kernel<<<8192, 256, 0, stream>>>(h, obuf, ln2g + l * 768, ln2b + l * 768, h, hbf);
  }
  pool_kernel<<<16, 256, 0, stream>>>(h, lens, ow, ob, out);
  (void)in_sizes;
  (void)n_in;
  (void)out_size;
  (void)ws_size;
}